// Round 1
// baseline (977.270 us; speedup 1.0000x reference)
//
#include <hip/hip_runtime.h>
#include <hip/hip_bf16.h>

// Problem dims (fixed by setup_inputs)
#define LQ 1024
#define MM 16
#define SS 64
#define EE 128
#define EV 128

#define MASK_VALUE -10000000.0f

// One block per (l,m) pair. 256 threads = 4 waves.
// Phase 1: q[l] -> LDS.
// Phase 2: scores[s] = dot(q, keys[l,m,s,:]) via float4 loads + 32-lane shuffle reduce.
// Phase 3: masked softmax over S=64 on wave 0.
// Phase 4: pooled[v] = sum_s w[s]*values[l,m,s,v] via float4 loads + LDS group reduce.
__global__ __launch_bounds__(256) void local_attn_kernel(
    const float* __restrict__ q,      // (L,E)
    const float* __restrict__ keys,   // (L,M,S,E)
    const float* __restrict__ vals,   // (L,M,S,EV)
    const int*   __restrict__ mask,   // (L,M,S) int32 (0/1)
    float* __restrict__ pooled,       // (L,M,EV)
    float* __restrict__ attw)         // (L,M,S)
{
    const int lm  = blockIdx.x;        // l*M + m
    const int l   = lm >> 4;           // / MM
    const int tid = threadIdx.x;

    __shared__ float  s_q[EE];
    __shared__ float  s_scores[SS];
    __shared__ float  s_w[SS];
    __shared__ float4 s_pacc[256];

    // ---- Phase 1: stage q row ----
    if (tid < EE) s_q[tid] = q[(size_t)l * EE + tid];
    __syncthreads();

    const int e4 = tid & 31;   // float4 column 0..31 (covers 128 floats)
    const int sg = tid >> 5;   // group 0..7
    float4 q4 = ((const float4*)s_q)[e4];

    // ---- Phase 2: scores ----
    // flat float4 index g = k*256 + tid  ->  s = g/32 = k*8 + sg, col = e4
    const float4* k4 = (const float4*)(keys + (size_t)lm * SS * EE);
    #pragma unroll
    for (int k = 0; k < 8; ++k) {
        const int s = k * 8 + sg;
        float4 kk = k4[(size_t)s * 32 + e4];
        float p = q4.x * kk.x + q4.y * kk.y + q4.z * kk.z + q4.w * kk.w;
        // reduce across the 32 lanes holding this row's columns
        #pragma unroll
        for (int off = 16; off > 0; off >>= 1)
            p += __shfl_xor(p, off, 64);
        if (e4 == 0) s_scores[s] = p;
    }
    __syncthreads();

    // ---- Phase 3: masked softmax (wave 0, lanes 0..63 = one row each) ----
    if (tid < SS) {
        const int mk = mask[(size_t)lm * SS + tid];
        float sc = s_scores[tid] + (mk ? 0.0f : MASK_VALUE);
        float mx = sc;
        #pragma unroll
        for (int off = 32; off > 0; off >>= 1)
            mx = fmaxf(mx, __shfl_xor(mx, off, 64));
        float e = __expf(sc - mx);
        float sum = e;
        #pragma unroll
        for (int off = 32; off > 0; off >>= 1)
            sum += __shfl_xor(sum, off, 64);
        float w = e / sum;
        s_w[tid] = w;
        attw[(size_t)lm * SS + tid] = w;
    }
    __syncthreads();

    // ---- Phase 4: pooled = w . values ----
    const float4* v4 = (const float4*)(vals + (size_t)lm * SS * EV);
    float4 acc = make_float4(0.f, 0.f, 0.f, 0.f);
    #pragma unroll
    for (int k = 0; k < 8; ++k) {
        const int s = k * 8 + sg;
        const float w = s_w[s];
        float4 vv = v4[(size_t)s * 32 + e4];
        acc.x += w * vv.x;
        acc.y += w * vv.y;
        acc.z += w * vv.z;
        acc.w += w * vv.w;
    }
    s_pacc[tid] = acc;
    __syncthreads();

    if (tid < 32) {
        float4 r = s_pacc[tid];
        #pragma unroll
        for (int g = 1; g < 8; ++g) {
            float4 t = s_pacc[g * 32 + tid];
            r.x += t.x; r.y += t.y; r.z += t.z; r.w += t.w;
        }
        ((float4*)(pooled + (size_t)lm * EV))[tid] = r;
    }
}

extern "C" void kernel_launch(void* const* d_in, const int* in_sizes, int n_in,
                              void* d_out, int out_size, void* d_ws, size_t ws_size,
                              hipStream_t stream) {
    const float* q    = (const float*)d_in[0];
    const float* keys = (const float*)d_in[1];
    const float* vals = (const float*)d_in[2];
    const int*   mask = (const int*)d_in[3];

    float* pooled = (float*)d_out;                               // (L,M,EV)
    float* attw   = (float*)d_out + (size_t)LQ * MM * EV;        // (L,M,S)

    local_attn_kernel<<<LQ * MM, 256, 0, stream>>>(q, keys, vals, mask, pooled, attw);
}